// Round 21
// baseline (212.500 us; speedup 1.0000x reference)
//
#include <hip/hip_runtime.h>

// Shape: (B=2, C=1, D=160, H=192, W=160) fp32. win=9/dim, win_size=9 (faithful bug).
#define B_ 2
#define D_ 160
#define H_ 192
#define W_ 160
#define W4_ (W_ / 4)
#define HW_ (H_ * W_)
#define DHW_ (D_ * HW_)
#define NV_ ((long long)B_ * D_ * H_ * W_)

// K1: block = (bz, y-quarter); full W staged in LDS with zero-filled halos.
#define YH1 48
#define NYH (H_ / YH1)       // 4
#define SROWS (YH1 + 8)      // 56 staged rows
#define SSTRH (W_ + 4)       // 164 halves per LDS row
#define YCH1 6               // rows per thread (8 yc x 40 xg = 320 thr)

// K2: interleaved-read z-march, ZCH=10 (measured traffic knee), prefetched.
#define ROWS2 8
#define ZCH2 10
#define NZC2 (D_ / ZCH2)     // 16
#define PAD 4
#define LROW (W_ + 2 * PAD)  // 168

// Interleaved A layout: [bz][y][c][x] in _Float16.
#define A_YSTRIDE ((size_t)5 * W_)
#define A_ZSTRIDE ((size_t)5 * HW_)

typedef _Float16 half4 __attribute__((ext_vector_type(4)));

__global__ void k_zero(double* acc) { *acc = 0.0; }

__device__ __forceinline__ void add4h(float4& d, const half4 v) {
    d.x += (float)v.x; d.y += (float)v.y; d.z += (float)v.z; d.w += (float)v.w;
}
__device__ __forceinline__ void sub4h(float4& d, const half4 v) {
    d.x -= (float)v.x; d.y -= (float)v.y; d.z -= (float)v.z; d.w -= (float)v.w;
}

// Accumulate (+/-) one staged row's 5 products into s[5] (4 x-cols).
template<int SGN>
__device__ __forceinline__ void accPr(float4 s[5], const half4 ha, const half4 hb) {
    const float4 a = make_float4((float)ha.x, (float)ha.y, (float)ha.z, (float)ha.w);
    const float4 b = make_float4((float)hb.x, (float)hb.y, (float)hb.z, (float)hb.w);
    if (SGN > 0) {
        s[0].x += a.x;     s[0].y += a.y;     s[0].z += a.z;     s[0].w += a.w;
        s[1].x += b.x;     s[1].y += b.y;     s[1].z += b.z;     s[1].w += b.w;
        s[2].x += a.x*a.x; s[2].y += a.y*a.y; s[2].z += a.z*a.z; s[2].w += a.w*a.w;
        s[3].x += b.x*b.x; s[3].y += b.y*b.y; s[3].z += b.z*b.z; s[3].w += b.w*b.w;
        s[4].x += a.x*b.x; s[4].y += a.y*b.y; s[4].z += a.z*b.z; s[4].w += a.w*b.w;
    } else {
        s[0].x -= a.x;     s[0].y -= a.y;     s[0].z -= a.z;     s[0].w -= a.w;
        s[1].x -= b.x;     s[1].y -= b.y;     s[1].z -= b.z;     s[1].w -= b.w;
        s[2].x -= a.x*a.x; s[2].y -= a.y*a.y; s[2].z -= a.z*a.z; s[2].w -= a.w*a.w;
        s[3].x -= b.x*b.x; s[3].y -= b.y*b.y; s[3].z -= b.z*b.z; s[3].w -= b.w*b.w;
        s[4].x -= a.x*b.x; s[4].y -= a.y*b.y; s[4].z -= a.z*b.z; s[4].w -= a.w*b.w;
    }
}

// ---------------------------------------------------------------------------
// K1: block = one (b,z) slice x one 48-row y-quarter. Stage 56 rows x full W
// of I,J in LDS fp16 (rows outside [0,H) zero-filled -> no boundary logic),
// then 40x8 threads run y-window running sums and write interleaved fp16 A.
// Per y the block writes 1600 B contiguous -> full-line writes, no RMW.
// LDS 36.7 KB -> 4 blocks/CU; grid 1280.
// ---------------------------------------------------------------------------
__global__ __launch_bounds__(320) void k1_ysum(const float* __restrict__ I,
                                               const float* __restrict__ J,
                                               _Float16* __restrict__ A) {
    __shared__ _Float16 sI[SROWS][SSTRH];    // 18.4 KB
    __shared__ _Float16 sJ[SROWS][SSTRH];    // 18.4 KB
    const int tid = threadIdx.x;             // 0..319
    const int yh  = blockIdx.x % NYH;
    const int bz  = blockIdx.x / NYH;        // b*D + z
    const int ylo = yh * YH1 - 4;            // staged row lr <-> global y = ylo+lr

    const float* Ib = I + (size_t)bz * HW_;
    const float* Jb = J + (size_t)bz * HW_;

    // ---- stage: 56 rows x 40 float4-groups = 2240 per map, 7 per thread ----
#pragma unroll
    for (int i = 0; i < 7; ++i) {
        const int idx = i * 320 + tid;       // 0..2239
        const int lr  = idx / 40;
        const int g   = idx - lr * 40;
        const int gy  = ylo + lr;
        half4 hi, hj;
        hi.x = hi.y = hi.z = hi.w = (_Float16)0.f;
        hj.x = hj.y = hj.z = hj.w = (_Float16)0.f;
        if (gy >= 0 && gy < H_) {
            const float4 vi = *(const float4*)(Ib + (size_t)gy * W_ + g * 4);
            const float4 vj = *(const float4*)(Jb + (size_t)gy * W_ + g * 4);
            hi.x = (_Float16)vi.x; hi.y = (_Float16)vi.y; hi.z = (_Float16)vi.z; hi.w = (_Float16)vi.w;
            hj.x = (_Float16)vj.x; hj.y = (_Float16)vj.y; hj.z = (_Float16)vj.z; hj.w = (_Float16)vj.w;
        }
        *(half4*)&sI[lr][g * 4] = hi;
        *(half4*)&sJ[lr][g * 4] = hj;
    }
    __syncthreads();

    // ---- compute: thread = (xg 0..39, yc 0..7); 6 rows each ----
    const int xg = tid % 40;
    const int yc = tid / 40;
    const int x4 = xg * 4;
    const int y0 = yh * YH1 + yc * YCH1;     // first output row
    const int l0 = yc * YCH1 + 4;            // its staged index

    _Float16* Ap = A + (size_t)bz * A_ZSTRIDE + x4;

    float4 s[5];
#pragma unroll
    for (int c = 0; c < 5; ++c) s[c] = make_float4(0.f, 0.f, 0.f, 0.f);

#pragma unroll
    for (int j = 0; j < 8; ++j)              // prime staged rows [l0-4, l0+3]
        accPr<+1>(s, *(const half4*)&sI[l0 - 4 + j][x4], *(const half4*)&sJ[l0 - 4 + j][x4]);

#pragma unroll
    for (int k = 0; k < YCH1; ++k) {
        const int ll = l0 + k + 4;           // lead (<= 55; zero rows clip top)
        accPr<+1>(s, *(const half4*)&sI[ll][x4], *(const half4*)&sJ[ll][x4]);
        if (k >= 1) {                        // trail: only rows actually added
            const int lt = l0 + k - 5;
            accPr<-1>(s, *(const half4*)&sI[lt][x4], *(const half4*)&sJ[lt][x4]);
        }
        _Float16* Ay = Ap + (size_t)(y0 + k) * A_YSTRIDE;
#pragma unroll
        for (int c = 0; c < 5; ++c) {
            half4 h;
            h.x = (_Float16)s[c].x; h.y = (_Float16)s[c].y;
            h.z = (_Float16)s[c].z; h.w = (_Float16)s[c].w;
            *(half4*)(Ay + c * W_) = h;
        }
    }
}

// x-window over one channel row of sbuf (padded, zero pads).
__device__ __forceinline__ float4 xwin(const float* rowp, int x4) {
    const float4 a0 = *(const float4*)(rowp + x4);
    const float4 a1 = *(const float4*)(rowp + x4 + 4);
    const float4 a2 = *(const float4*)(rowp + x4 + 8);
    const float o0 = a0.x + a0.y + a0.z + a0.w + a1.x + a1.y + a1.z + a1.w + a2.x;
    const float o1 = o0 - a0.x + a2.y;
    const float o2 = o1 - a0.y + a2.z;
    const float o3 = o2 - a0.z + a2.w;
    return make_float4(o0, o1, o2, o3);
}

__device__ __forceinline__ float cc4(const float4 S0, const float4 S1, const float4 S2,
                                     const float4 S3, const float4 S4) {
    const float inv9 = 1.0f / 9.0f;
    float a = 0.f;
    { const float cr = S4.x - S1.x * S0.x * inv9;
      const float iv = S2.x - S0.x * S0.x * inv9;
      const float jv = S3.x - S1.x * S1.x * inv9;
      a += cr * cr / (iv * jv + 1e-5f); }
    { const float cr = S4.y - S1.y * S0.y * inv9;
      const float iv = S2.y - S0.y * S0.y * inv9;
      const float jv = S3.y - S1.y * S1.y * inv9;
      a += cr * cr / (iv * jv + 1e-5f); }
    { const float cr = S4.z - S1.z * S0.z * inv9;
      const float iv = S2.z - S0.z * S0.z * inv9;
      const float jv = S3.z - S1.z * S1.z * inv9;
      a += cr * cr / (iv * jv + 1e-5f); }
    { const float cr = S4.w - S1.w * S0.w * inv9;
      const float iv = S2.w - S0.w * S0.w * inv9;
      const float jv = S3.w - S1.w * S1.w * inv9;
      a += cr * cr / (iv * jv + 1e-5f); }
    return a;
}

// Prefetch a step's lead+trail slices into NAMED half4 registers (no arrays,
// no structs -> no scratch; addresses clamped so loads are unconditional).
#define K2_ISSUE(K, P) do {                                                   \
    int zi_ = z0 + (K) + 4; if (zi_ > D_ - 1) zi_ = D_ - 1;                   \
    int zo_ = z0 + (K) - 5; if (zo_ < 0) zo_ = 0;                             \
    const _Float16* pi_ = Abase + (size_t)zi_ * A_ZSTRIDE;                    \
    const _Float16* po_ = Abase + (size_t)zo_ * A_ZSTRIDE;                    \
    P##l0 = *(const half4*)(pi_ + 0 * W_);                                    \
    P##l1 = *(const half4*)(pi_ + 1 * W_);                                    \
    P##l2 = *(const half4*)(pi_ + 2 * W_);                                    \
    P##l3 = *(const half4*)(pi_ + 3 * W_);                                    \
    P##l4 = *(const half4*)(pi_ + 4 * W_);                                    \
    P##t0 = *(const half4*)(po_ + 0 * W_);                                    \
    P##t1 = *(const half4*)(po_ + 1 * W_);                                    \
    P##t2 = *(const half4*)(po_ + 2 * W_);                                    \
    P##t3 = *(const half4*)(po_ + 3 * W_);                                    \
    P##t4 = *(const half4*)(po_ + 4 * W_);                                    \
} while (0)

#define K2_STEP(K, P) do {                                                    \
    if (z0 + (K) + 4 < D_) {                                                  \
        add4h(s0, P##l0); add4h(s1, P##l1); add4h(s2, P##l2);                 \
        add4h(s3, P##l3); add4h(s4, P##l4);                                   \
    }                                                                         \
    if (z0 + (K) - 5 >= 0) {                                                  \
        sub4h(s0, P##t0); sub4h(s1, P##t1); sub4h(s2, P##t2);                 \
        sub4h(s3, P##t3); sub4h(s4, P##t4);                                   \
    }                                                                         \
    *(float4*)&sbuf[r][0][PAD + x4] = s0;                                     \
    *(float4*)&sbuf[r][1][PAD + x4] = s1;                                     \
    *(float4*)&sbuf[r][2][PAD + x4] = s2;                                     \
    *(float4*)&sbuf[r][3][PAD + x4] = s3;                                     \
    *(float4*)&sbuf[r][4][PAD + x4] = s4;                                     \
    __syncthreads();                                                          \
    {                                                                         \
        const float4 S0_ = xwin(&sbuf[r][0][0], x4);                          \
        const float4 S1_ = xwin(&sbuf[r][1][0], x4);                          \
        const float4 S2_ = xwin(&sbuf[r][2][0], x4);                          \
        const float4 S3_ = xwin(&sbuf[r][3][0], x4);                          \
        const float4 S4_ = xwin(&sbuf[r][4][0], x4);                          \
        local += cc4(S0_, S1_, S2_, S3_, S4_);                                \
    }                                                                         \
    __syncthreads();                                                          \
} while (0)

// ---------------------------------------------------------------------------
// K2: fused z-window + x-window (LDS) + cc + reduction, with depth-1
// prefetch in named registers (ping-pong A/B packs). ZCH=10, grid 768.
// ---------------------------------------------------------------------------
__global__ __launch_bounds__(320) void k2_zxcc(const _Float16* __restrict__ A,
                                               double* __restrict__ acc) {
    __shared__ float sbuf[ROWS2][5][LROW];   // 26.88 KB
    __shared__ float red[512];
    const int tid = threadIdx.x;             // 0..319
    const int r   = tid / W4_;               // 0..7
    const int l   = tid - r * W4_;           // 0..39
    const int x4  = l * 4;
    const int blk = blockIdx.x;
    const int zc  = blk % NZC2;
    const int rp  = blk / NZC2;              // 0..47
    const int gy  = rp * ROWS2 + r;          // 0..383
    const int b   = gy / H_;
    const int yy  = gy - b * H_;
    const int z0  = zc * ZCH2;

    {   // zero LDS once (pads must be 0; interior overwritten every step)
        float* p = &sbuf[0][0][0];
        for (int i = tid; i < ROWS2 * 5 * LROW; i += ROWS2 * W4_) p[i] = 0.f;
    }

    const _Float16* Abase = A + (size_t)b * D_ * A_ZSTRIDE + (size_t)yy * A_YSTRIDE + x4;

    float4 s0 = make_float4(0.f, 0.f, 0.f, 0.f);
    float4 s1 = s0, s2 = s0, s3 = s0, s4 = s0;
#pragma unroll
    for (int j = 0; j < 9; ++j) {            // prime slices [z0-5, z0+3]
        const int zi = z0 - 5 + j;
        if (zi >= 0) {
            const _Float16* Az = Abase + (size_t)zi * A_ZSTRIDE;
            add4h(s0, *(const half4*)(Az + 0 * W_));
            add4h(s1, *(const half4*)(Az + 1 * W_));
            add4h(s2, *(const half4*)(Az + 2 * W_));
            add4h(s3, *(const half4*)(Az + 3 * W_));
            add4h(s4, *(const half4*)(Az + 4 * W_));
        }
    }
    __syncthreads();                         // LDS zero visible

    float local = 0.f;
    half4 Al0, Al1, Al2, Al3, Al4, At0, At1, At2, At3, At4;
    half4 Bl0, Bl1, Bl2, Bl3, Bl4, Bt0, Bt1, Bt2, Bt3, Bt4;

    K2_ISSUE(0, A);
#pragma unroll
    for (int kk = 0; kk < ZCH2; kk += 2) {
        K2_ISSUE(kk + 1, B);                 // in flight across step kk
        K2_STEP(kk, A);
        K2_ISSUE(kk + 2, A);                 // kk+2==ZCH2 -> clamped, unused
        K2_STEP(kk + 1, B);
    }

    red[tid] = local;
    if (tid < 192) red[320 + tid] = 0.f;
    __syncthreads();
    for (int off = 256; off > 0; off >>= 1) {
        if (tid < off) red[tid] += red[tid + off];
        __syncthreads();
    }
    if (tid == 0) atomicAdd(acc, (double)red[0]);
}

// ---------------------------------------------------------------------------
// Fallback (workspace too small): direct clipped 9x9x9 sums per voxel.
// ---------------------------------------------------------------------------
__global__ void p_direct(const float* __restrict__ I, const float* __restrict__ J,
                         double* __restrict__ acc) {
    const long long idx = (long long)blockIdx.x * blockDim.x + threadIdx.x;
    float local = 0.f;
    if (idx < NV_) {
        const int x = (int)(idx % W_);
        long long t = idx / W_;
        const int y = (int)(t % H_);
        t /= H_;
        const int z = (int)(t % D_);
        const int b = (int)(t / D_);
        const int z0 = max(z - 4, 0), z1 = min(z + 4, D_ - 1);
        const int y0 = max(y - 4, 0), y1 = min(y + 4, H_ - 1);
        const int x0 = max(x - 4, 0), x1 = min(x + 4, W_ - 1);
        float sI = 0.f, sJ = 0.f, sI2 = 0.f, sJ2 = 0.f, sIJ = 0.f;
        for (int zz = z0; zz <= z1; ++zz)
            for (int yy = y0; yy <= y1; ++yy) {
                const size_t row = ((size_t)(b * D_ + zz) * H_ + yy) * W_;
                for (int xx = x0; xx <= x1; ++xx) {
                    const float a = I[row + xx];
                    const float bb = J[row + xx];
                    sI += a; sJ += bb; sI2 += a * a; sJ2 += bb * bb; sIJ += a * bb;
                }
            }
        const float inv9 = 1.0f / 9.0f;
        const float cross = sIJ - sJ * sI * inv9;
        const float iv    = sI2 - sI * sI * inv9;
        const float jv    = sJ2 - sJ * sJ * inv9;
        local = cross * cross / (iv * jv + 1e-5f);
    }
    __shared__ float red[256];
    red[threadIdx.x] = local;
    __syncthreads();
    for (int off = 128; off > 0; off >>= 1) {
        if (threadIdx.x < off) red[threadIdx.x] += red[threadIdx.x + off];
        __syncthreads();
    }
    if (threadIdx.x == 0) atomicAdd(acc, (double)red[0]);
}

__global__ void k_final(const double* __restrict__ acc, float* __restrict__ out) {
    out[0] = (float)(-(*acc) / (double)NV_);
}

extern "C" void kernel_launch(void* const* d_in, const int* in_sizes, int n_in,
                              void* d_out, int out_size, void* d_ws, size_t ws_size,
                              hipStream_t stream) {
    const float* I = (const float*)d_in[0];  // y_true
    const float* J = (const float*)d_in[1];  // y_pred
    float* out = (float*)d_out;

    const size_t needA = (size_t)5 * B_ * DHW_ * sizeof(_Float16);  // 98.3 MB
    if (ws_size >= 1024 + needA) {
        double* acc = (double*)d_ws;
        _Float16* A = (_Float16*)((char*)d_ws + 1024);
        k_zero<<<1, 1, 0, stream>>>(acc);
        k1_ysum<<<B_ * D_ * NYH, 320, 0, stream>>>(I, J, A);
        k2_zxcc<<<NZC2 * (B_ * H_ / ROWS2), ROWS2 * W4_, 0, stream>>>(A, acc);
        k_final<<<1, 1, 0, stream>>>(acc, out);
    } else if (ws_size >= sizeof(double)) {
        double* acc = (double*)d_ws;
        k_zero<<<1, 1, 0, stream>>>(acc);
        p_direct<<<(int)((NV_ + 255) / 256), 256, 0, stream>>>(I, J, acc);
        k_final<<<1, 1, 0, stream>>>(acc, out);
    }
}

// Round 22
// 145.120 us; speedup vs baseline: 1.4643x; 1.4643x over previous
//
#include <hip/hip_runtime.h>

// Shape: (B=2, C=1, D=160, H=192, W=160) fp32. win=9/dim, win_size=9 (faithful bug).
#define B_ 2
#define D_ 160
#define H_ 192
#define W_ 160
#define HW_ (H_ * W_)
#define DHW_ (D_ * HW_)
#define NV_ ((long long)B_ * D_ * H_ * W_)

// K1: block = (bz, y-quarter); full W staged in LDS with zero-filled halos.
#define YH1 48
#define NYH (H_ / YH1)       // 4
#define SROWS (YH1 + 8)      // 56 staged rows
#define SSTRH (W_ + 4)       // 164 halves per LDS stage row
#define YCH1 6               // rows per thread (8 yc x 40 xg = 320 thr)

// K2: no-LDS no-barrier z-march; thread = 4 outputs w/ 12-wide z-sums.
#define ZCH2 10
#define NZC2 (D_ / ZCH2)     // 16

// Padded interleaved A: [bz][y][c][xpad], xpad = 4 + 160 + 4 = 168 halves.
#define RW_ 168
#define A_Y ((size_t)5 * RW_)        // 840 halves per y
#define A_Z ((size_t)H_ * A_Y)      // 161280 halves per slice

typedef _Float16 half4 __attribute__((ext_vector_type(4)));

__global__ void k_zero(double* acc) { *acc = 0.0; }

__device__ __forceinline__ void add4h(float4& d, const half4 v) {
    d.x += (float)v.x; d.y += (float)v.y; d.z += (float)v.z; d.w += (float)v.w;
}
__device__ __forceinline__ void sub4h(float4& d, const half4 v) {
    d.x -= (float)v.x; d.y -= (float)v.y; d.z -= (float)v.z; d.w -= (float)v.w;
}

// Accumulate (+/-) one staged row's 5 products into s[5] (4 x-cols).
template<int SGN>
__device__ __forceinline__ void accPr(float4 s[5], const half4 ha, const half4 hb) {
    const float4 a = make_float4((float)ha.x, (float)ha.y, (float)ha.z, (float)ha.w);
    const float4 b = make_float4((float)hb.x, (float)hb.y, (float)hb.z, (float)hb.w);
    if (SGN > 0) {
        s[0].x += a.x;     s[0].y += a.y;     s[0].z += a.z;     s[0].w += a.w;
        s[1].x += b.x;     s[1].y += b.y;     s[1].z += b.z;     s[1].w += b.w;
        s[2].x += a.x*a.x; s[2].y += a.y*a.y; s[2].z += a.z*a.z; s[2].w += a.w*a.w;
        s[3].x += b.x*b.x; s[3].y += b.y*b.y; s[3].z += b.z*b.z; s[3].w += b.w*b.w;
        s[4].x += a.x*b.x; s[4].y += a.y*b.y; s[4].z += a.z*b.z; s[4].w += a.w*b.w;
    } else {
        s[0].x -= a.x;     s[0].y -= a.y;     s[0].z -= a.z;     s[0].w -= a.w;
        s[1].x -= b.x;     s[1].y -= b.y;     s[1].z -= b.z;     s[1].w -= b.w;
        s[2].x -= a.x*a.x; s[2].y -= a.y*a.y; s[2].z -= a.z*a.z; s[2].w -= a.w*a.w;
        s[3].x -= b.x*b.x; s[3].y -= b.y*b.y; s[3].z -= b.z*b.z; s[3].w -= b.w*b.w;
        s[4].x -= a.x*b.x; s[4].y -= a.y*b.y; s[4].z -= a.z*b.z; s[4].w -= a.w*b.w;
    }
}

// ---------------------------------------------------------------------------
// K1: block = one (b,z) slice x one 48-row y-quarter. Stage 56 rows x full W
// of I,J in LDS fp16 (rows outside [0,H) zero-filled), run y-window running
// sums, write padded interleaved fp16 A (full-line contiguous stores; edge
// lanes zero the 8-B pads each row). LDS 36.7 KB -> 4 blocks/CU; grid 1280.
// Structure verified (absmax 0.0) in R21; only store addressing changed.
// ---------------------------------------------------------------------------
__global__ __launch_bounds__(320) void k1_ysum(const float* __restrict__ I,
                                               const float* __restrict__ J,
                                               _Float16* __restrict__ A) {
    __shared__ _Float16 sI[SROWS][SSTRH];    // 18.4 KB
    __shared__ _Float16 sJ[SROWS][SSTRH];    // 18.4 KB
    const int tid = threadIdx.x;             // 0..319
    const int yh  = blockIdx.x % NYH;
    const int bz  = blockIdx.x / NYH;        // b*D + z
    const int ylo = yh * YH1 - 4;            // staged row lr <-> global y = ylo+lr

    const float* Ib = I + (size_t)bz * HW_;
    const float* Jb = J + (size_t)bz * HW_;

    // ---- stage: 56 rows x 40 float4-groups = 2240 per map, 7 per thread ----
#pragma unroll
    for (int i = 0; i < 7; ++i) {
        const int idx = i * 320 + tid;       // 0..2239
        const int lr  = idx / 40;
        const int g   = idx - lr * 40;
        const int gy  = ylo + lr;
        half4 hi, hj;
        hi.x = hi.y = hi.z = hi.w = (_Float16)0.f;
        hj.x = hj.y = hj.z = hj.w = (_Float16)0.f;
        if (gy >= 0 && gy < H_) {
            const float4 vi = *(const float4*)(Ib + (size_t)gy * W_ + g * 4);
            const float4 vj = *(const float4*)(Jb + (size_t)gy * W_ + g * 4);
            hi.x = (_Float16)vi.x; hi.y = (_Float16)vi.y; hi.z = (_Float16)vi.z; hi.w = (_Float16)vi.w;
            hj.x = (_Float16)vj.x; hj.y = (_Float16)vj.y; hj.z = (_Float16)vj.z; hj.w = (_Float16)vj.w;
        }
        *(half4*)&sI[lr][g * 4] = hi;
        *(half4*)&sJ[lr][g * 4] = hj;
    }
    __syncthreads();

    // ---- compute: thread = (xg 0..39, yc 0..7); 6 rows each ----
    const int xg = tid % 40;
    const int yc = tid / 40;
    const int x4 = xg * 4;
    const int y0 = yh * YH1 + yc * YCH1;     // first output row
    const int l0 = yc * YCH1 + 4;            // its staged index

    _Float16* Ap = A + (size_t)bz * A_Z;

    float4 s[5];
#pragma unroll
    for (int c = 0; c < 5; ++c) s[c] = make_float4(0.f, 0.f, 0.f, 0.f);

#pragma unroll
    for (int j = 0; j < 8; ++j)              // prime staged rows [l0-4, l0+3]
        accPr<+1>(s, *(const half4*)&sI[l0 - 4 + j][x4], *(const half4*)&sJ[l0 - 4 + j][x4]);

    half4 zer;
    zer.x = zer.y = zer.z = zer.w = (_Float16)0.f;

#pragma unroll
    for (int k = 0; k < YCH1; ++k) {
        const int ll = l0 + k + 4;           // lead (<= 55; zero rows clip)
        accPr<+1>(s, *(const half4*)&sI[ll][x4], *(const half4*)&sJ[ll][x4]);
        if (k >= 1) {                        // trail: only rows actually added
            const int lt = l0 + k - 5;
            accPr<-1>(s, *(const half4*)&sI[lt][x4], *(const half4*)&sJ[lt][x4]);
        }
        _Float16* Ay = Ap + (size_t)(y0 + k) * A_Y;
#pragma unroll
        for (int c = 0; c < 5; ++c) {
            half4 h;
            h.x = (_Float16)s[c].x; h.y = (_Float16)s[c].y;
            h.z = (_Float16)s[c].z; h.w = (_Float16)s[c].w;
            *(half4*)(Ay + c * RW_ + 4 + x4) = h;        // data at pad offset 4
            if (xg == 0)  *(half4*)(Ay + c * RW_)       = zer;   // left pad
            if (xg == 39) *(half4*)(Ay + c * RW_ + 164) = zer;   // right pad
        }
    }
}

__device__ __forceinline__ float cc4(const float4 S0, const float4 S1, const float4 S2,
                                     const float4 S3, const float4 S4) {
    const float inv9 = 1.0f / 9.0f;
    float a = 0.f;
    { const float cr = S4.x - S1.x * S0.x * inv9;
      const float iv = S2.x - S0.x * S0.x * inv9;
      const float jv = S3.x - S1.x * S1.x * inv9;
      a += cr * cr / (iv * jv + 1e-5f); }
    { const float cr = S4.y - S1.y * S0.y * inv9;
      const float iv = S2.y - S0.y * S0.y * inv9;
      const float jv = S3.y - S1.y * S1.y * inv9;
      a += cr * cr / (iv * jv + 1e-5f); }
    { const float cr = S4.z - S1.z * S0.z * inv9;
      const float iv = S2.z - S0.z * S0.z * inv9;
      const float jv = S3.z - S1.z * S1.z * inv9;
      a += cr * cr / (iv * jv + 1e-5f); }
    { const float cr = S4.w - S1.w * S0.w * inv9;
      const float iv = S2.w - S0.w * S0.w * inv9;
      const float jv = S3.w - S1.w * S1.w * inv9;
      a += cr * cr / (iv * jv + 1e-5f); }
    return a;
}

// ---------------------------------------------------------------------------
// K2: z-window + register x-window + cc + reduction. NO LDS, NO BARRIERS in
// the hot loop. Thread owns 4 outputs via 12-wide z-running sums (s[5][3],
// statically indexed). Per step: 15 lead + 15 trail aligned 8-B loads
// (block-uniform branches), register sliding window, cc. ZCH=10, grid 768.
// ---------------------------------------------------------------------------
__global__ __launch_bounds__(320) void k2_xzcc(const _Float16* __restrict__ A,
                                               double* __restrict__ acc) {
    const int tid = threadIdx.x;             // 0..319
    const int xg  = tid % 40;                // 0..39
    const int yl  = tid / 40;                // 0..7
    const int blk = blockIdx.x;
    const int zc  = blk % NZC2;
    const int rp  = blk / NZC2;              // 0..47
    const int gy  = rp * 8 + yl;             // 0..383
    const int b   = gy / H_;
    const int yy  = gy - b * H_;
    const int z0  = zc * ZCH2;
    const int xp  = 4 * xg;                  // padded col idx of window start

    const _Float16* base = A + (size_t)(b * D_) * A_Z + (size_t)yy * A_Y + xp;

    float4 s[5][3];
#pragma unroll
    for (int c = 0; c < 5; ++c)
#pragma unroll
        for (int t = 0; t < 3; ++t) s[c][t] = make_float4(0.f, 0.f, 0.f, 0.f);

#pragma unroll 2
    for (int j = 0; j < 9; ++j) {            // prime slices [z0-5, z0+3]
        const int zi = z0 - 5 + j;           // z0+3 <= 153 < D_
        if (zi >= 0) {
            const _Float16* p = base + (size_t)zi * A_Z;
#pragma unroll
            for (int c = 0; c < 5; ++c) {
                const _Float16* q = p + c * RW_;
                add4h(s[c][0], *(const half4*)q);
                add4h(s[c][1], *(const half4*)(q + 4));
                add4h(s[c][2], *(const half4*)(q + 8));
            }
        }
    }

    float local = 0.f;
#pragma unroll 2
    for (int k = 0; k < ZCH2; ++k) {
        const int zi = z0 + k + 4;           // block-uniform branch
        if (zi < D_) {
            const _Float16* p = base + (size_t)zi * A_Z;
#pragma unroll
            for (int c = 0; c < 5; ++c) {
                const _Float16* q = p + c * RW_;
                add4h(s[c][0], *(const half4*)q);
                add4h(s[c][1], *(const half4*)(q + 4));
                add4h(s[c][2], *(const half4*)(q + 8));
            }
        }
        const int zo = z0 + k - 5;
        if (zo >= 0) {
            const _Float16* p = base + (size_t)zo * A_Z;
#pragma unroll
            for (int c = 0; c < 5; ++c) {
                const _Float16* q = p + c * RW_;
                sub4h(s[c][0], *(const half4*)q);
                sub4h(s[c][1], *(const half4*)(q + 4));
                sub4h(s[c][2], *(const half4*)(q + 8));
            }
        }
        float4 S5[5];
#pragma unroll
        for (int c = 0; c < 5; ++c) {
            const float4 u = s[c][0], m = s[c][1], w = s[c][2];
            const float o0 = u.x + u.y + u.z + u.w + m.x + m.y + m.z + m.w + w.x;
            const float o1 = o0 - u.x + w.y;
            const float o2 = o1 - u.y + w.z;
            const float o3 = o2 - u.z + w.w;
            S5[c] = make_float4(o0, o1, o2, o3);
        }
        local += cc4(S5[0], S5[1], S5[2], S5[3], S5[4]);
    }

    __shared__ float red[512];
    red[tid] = local;
    if (tid < 192) red[320 + tid] = 0.f;
    __syncthreads();
    for (int off = 256; off > 0; off >>= 1) {
        if (tid < off) red[tid] += red[tid + off];
        __syncthreads();
    }
    if (tid == 0) atomicAdd(acc, (double)red[0]);
}

// ---------------------------------------------------------------------------
// Fallback (workspace too small): direct clipped 9x9x9 sums per voxel.
// ---------------------------------------------------------------------------
__global__ void p_direct(const float* __restrict__ I, const float* __restrict__ J,
                         double* __restrict__ acc) {
    const long long idx = (long long)blockIdx.x * blockDim.x + threadIdx.x;
    float local = 0.f;
    if (idx < NV_) {
        const int x = (int)(idx % W_);
        long long t = idx / W_;
        const int y = (int)(t % H_);
        t /= H_;
        const int z = (int)(t % D_);
        const int b = (int)(t / D_);
        const int z0 = max(z - 4, 0), z1 = min(z + 4, D_ - 1);
        const int y0 = max(y - 4, 0), y1 = min(y + 4, H_ - 1);
        const int x0 = max(x - 4, 0), x1 = min(x + 4, W_ - 1);
        float sI = 0.f, sJ = 0.f, sI2 = 0.f, sJ2 = 0.f, sIJ = 0.f;
        for (int zz = z0; zz <= z1; ++zz)
            for (int yy = y0; yy <= y1; ++yy) {
                const size_t row = ((size_t)(b * D_ + zz) * H_ + yy) * W_;
                for (int xx = x0; xx <= x1; ++xx) {
                    const float a = I[row + xx];
                    const float bb = J[row + xx];
                    sI += a; sJ += bb; sI2 += a * a; sJ2 += bb * bb; sIJ += a * bb;
                }
            }
        const float inv9 = 1.0f / 9.0f;
        const float cross = sIJ - sJ * sI * inv9;
        const float iv    = sI2 - sI * sI * inv9;
        const float jv    = sJ2 - sJ * sJ * inv9;
        local = cross * cross / (iv * jv + 1e-5f);
    }
    __shared__ float red[256];
    red[threadIdx.x] = local;
    __syncthreads();
    for (int off = 128; off > 0; off >>= 1) {
        if (threadIdx.x < off) red[threadIdx.x] += red[threadIdx.x + off];
        __syncthreads();
    }
    if (threadIdx.x == 0) atomicAdd(acc, (double)red[0]);
}

__global__ void k_final(const double* __restrict__ acc, float* __restrict__ out) {
    out[0] = (float)(-(*acc) / (double)NV_);
}

extern "C" void kernel_launch(void* const* d_in, const int* in_sizes, int n_in,
                              void* d_out, int out_size, void* d_ws, size_t ws_size,
                              hipStream_t stream) {
    const float* I = (const float*)d_in[0];  // y_true
    const float* J = (const float*)d_in[1];  // y_pred
    float* out = (float*)d_out;

    const size_t needA = (size_t)B_ * D_ * A_Z * sizeof(_Float16);  // 103.2 MB
    if (ws_size >= 1024 + needA) {
        double* acc = (double*)d_ws;
        _Float16* A = (_Float16*)((char*)d_ws + 1024);
        k_zero<<<1, 1, 0, stream>>>(acc);
        k1_ysum<<<B_ * D_ * NYH, 320, 0, stream>>>(I, J, A);
        k2_xzcc<<<NZC2 * (B_ * H_ / 8), 320, 0, stream>>>(A, acc);
        k_final<<<1, 1, 0, stream>>>(acc, out);
    } else if (ws_size >= sizeof(double)) {
        double* acc = (double*)d_ws;
        k_zero<<<1, 1, 0, stream>>>(acc);
        p_direct<<<(int)((NV_ + 255) / 256), 256, 0, stream>>>(I, J, acc);
        k_final<<<1, 1, 0, stream>>>(acc, out);
    }
}

// Round 23
// 106.488 us; speedup vs baseline: 1.9955x; 1.3628x over previous
//
#include <hip/hip_runtime.h>

// Shape: (B=2, C=1, D=160, H=192, W=160) fp32. win=9/dim, win_size=9 (faithful bug).
#define B_ 2
#define D_ 160
#define H_ 192
#define W_ 160
#define HW_ (H_ * W_)
#define DHW_ (D_ * HW_)
#define NV_ ((long long)B_ * D_ * H_ * W_)

// K1: block = (bz, y-quarter); full W staged in LDS with zero-filled halos.
#define YH1 48
#define NYH (H_ / YH1)       // 4
#define SROWS (YH1 + 8)      // 56 staged rows
#define SSTRH (W_ + 4)       // 164 halves per LDS stage row
#define YCH1 6               // rows per thread (8 yc x 40 xg = 320 thr)

// K2: LDS x-window, double-buffered, 1 barrier/step; ROWS2=4 -> 1536 blocks.
#define ROWS2 4
#define ZCH2 10
#define NZC2 (D_ / ZCH2)     // 16
#define NRP (B_ * H_ / ROWS2) // 96

// Padded interleaved A: [bz][y][c][xpad], xpad = 4 + 160 + 4 = 168 halves.
#define RW_ 168
#define A_Y ((size_t)5 * RW_)        // 840 halves per y
#define A_Z ((size_t)H_ * A_Y)      // 161280 halves per slice

typedef _Float16 half4 __attribute__((ext_vector_type(4)));

__global__ void k_zero(double* acc) { *acc = 0.0; }

__device__ __forceinline__ void add4h(float4& d, const half4 v) {
    d.x += (float)v.x; d.y += (float)v.y; d.z += (float)v.z; d.w += (float)v.w;
}
__device__ __forceinline__ void sub4h(float4& d, const half4 v) {
    d.x -= (float)v.x; d.y -= (float)v.y; d.z -= (float)v.z; d.w -= (float)v.w;
}

// Accumulate (+/-) one staged row's 5 products into s[5] (4 x-cols).
template<int SGN>
__device__ __forceinline__ void accPr(float4 s[5], const half4 ha, const half4 hb) {
    const float4 a = make_float4((float)ha.x, (float)ha.y, (float)ha.z, (float)ha.w);
    const float4 b = make_float4((float)hb.x, (float)hb.y, (float)hb.z, (float)hb.w);
    if (SGN > 0) {
        s[0].x += a.x;     s[0].y += a.y;     s[0].z += a.z;     s[0].w += a.w;
        s[1].x += b.x;     s[1].y += b.y;     s[1].z += b.z;     s[1].w += b.w;
        s[2].x += a.x*a.x; s[2].y += a.y*a.y; s[2].z += a.z*a.z; s[2].w += a.w*a.w;
        s[3].x += b.x*b.x; s[3].y += b.y*b.y; s[3].z += b.z*b.z; s[3].w += b.w*b.w;
        s[4].x += a.x*b.x; s[4].y += a.y*b.y; s[4].z += a.z*b.z; s[4].w += a.w*b.w;
    } else {
        s[0].x -= a.x;     s[0].y -= a.y;     s[0].z -= a.z;     s[0].w -= a.w;
        s[1].x -= b.x;     s[1].y -= b.y;     s[1].z -= b.z;     s[1].w -= b.w;
        s[2].x -= a.x*a.x; s[2].y -= a.y*a.y; s[2].z -= a.z*a.z; s[2].w -= a.w*a.w;
        s[3].x -= b.x*b.x; s[3].y -= b.y*b.y; s[3].z -= b.z*b.z; s[3].w -= b.w*b.w;
        s[4].x -= a.x*b.x; s[4].y -= a.y*b.y; s[4].z -= a.z*b.z; s[4].w -= a.w*b.w;
    }
}

// ---------------------------------------------------------------------------
// K1: block = one (b,z) slice x one 48-row y-quarter. Stage 56 rows x full W
// of I,J in LDS fp16 (rows outside [0,H) zero-filled), run y-window running
// sums, write padded interleaved fp16 A (full-line contiguous stores; edge
// lanes zero the pads). LDS 36.7 KB -> 4 blocks/CU; grid 1280.
// Verified absmax 0.0 in R22.
// ---------------------------------------------------------------------------
__global__ __launch_bounds__(320) void k1_ysum(const float* __restrict__ I,
                                               const float* __restrict__ J,
                                               _Float16* __restrict__ A) {
    __shared__ _Float16 sI[SROWS][SSTRH];    // 18.4 KB
    __shared__ _Float16 sJ[SROWS][SSTRH];    // 18.4 KB
    const int tid = threadIdx.x;             // 0..319
    const int yh  = blockIdx.x % NYH;
    const int bz  = blockIdx.x / NYH;        // b*D + z
    const int ylo = yh * YH1 - 4;            // staged row lr <-> global y = ylo+lr

    const float* Ib = I + (size_t)bz * HW_;
    const float* Jb = J + (size_t)bz * HW_;

#pragma unroll
    for (int i = 0; i < 7; ++i) {
        const int idx = i * 320 + tid;       // 0..2239
        const int lr  = idx / 40;
        const int g   = idx - lr * 40;
        const int gy  = ylo + lr;
        half4 hi, hj;
        hi.x = hi.y = hi.z = hi.w = (_Float16)0.f;
        hj.x = hj.y = hj.z = hj.w = (_Float16)0.f;
        if (gy >= 0 && gy < H_) {
            const float4 vi = *(const float4*)(Ib + (size_t)gy * W_ + g * 4);
            const float4 vj = *(const float4*)(Jb + (size_t)gy * W_ + g * 4);
            hi.x = (_Float16)vi.x; hi.y = (_Float16)vi.y; hi.z = (_Float16)vi.z; hi.w = (_Float16)vi.w;
            hj.x = (_Float16)vj.x; hj.y = (_Float16)vj.y; hj.z = (_Float16)vj.z; hj.w = (_Float16)vj.w;
        }
        *(half4*)&sI[lr][g * 4] = hi;
        *(half4*)&sJ[lr][g * 4] = hj;
    }
    __syncthreads();

    const int xg = tid % 40;
    const int yc = tid / 40;
    const int x4 = xg * 4;
    const int y0 = yh * YH1 + yc * YCH1;     // first output row
    const int l0 = yc * YCH1 + 4;            // its staged index

    _Float16* Ap = A + (size_t)bz * A_Z;

    float4 s[5];
#pragma unroll
    for (int c = 0; c < 5; ++c) s[c] = make_float4(0.f, 0.f, 0.f, 0.f);

#pragma unroll
    for (int j = 0; j < 8; ++j)              // prime staged rows [l0-4, l0+3]
        accPr<+1>(s, *(const half4*)&sI[l0 - 4 + j][x4], *(const half4*)&sJ[l0 - 4 + j][x4]);

    half4 zer;
    zer.x = zer.y = zer.z = zer.w = (_Float16)0.f;

#pragma unroll
    for (int k = 0; k < YCH1; ++k) {
        const int ll = l0 + k + 4;           // lead (<= 55; zero rows clip)
        accPr<+1>(s, *(const half4*)&sI[ll][x4], *(const half4*)&sJ[ll][x4]);
        if (k >= 1) {                        // trail: only rows actually added
            const int lt = l0 + k - 5;
            accPr<-1>(s, *(const half4*)&sI[lt][x4], *(const half4*)&sJ[lt][x4]);
        }
        _Float16* Ay = Ap + (size_t)(y0 + k) * A_Y;
#pragma unroll
        for (int c = 0; c < 5; ++c) {
            half4 h;
            h.x = (_Float16)s[c].x; h.y = (_Float16)s[c].y;
            h.z = (_Float16)s[c].z; h.w = (_Float16)s[c].w;
            *(half4*)(Ay + c * RW_ + 4 + x4) = h;
            if (xg == 0)  *(half4*)(Ay + c * RW_)       = zer;
            if (xg == 39) *(half4*)(Ay + c * RW_ + 164) = zer;
        }
    }
}

__device__ __forceinline__ float cc4(const float4 S0, const float4 S1, const float4 S2,
                                     const float4 S3, const float4 S4) {
    const float inv9 = 1.0f / 9.0f;
    float a = 0.f;
    { const float cr = S4.x - S1.x * S0.x * inv9;
      const float iv = S2.x - S0.x * S0.x * inv9;
      const float jv = S3.x - S1.x * S1.x * inv9;
      a += cr * cr / (iv * jv + 1e-5f); }
    { const float cr = S4.y - S1.y * S0.y * inv9;
      const float iv = S2.y - S0.y * S0.y * inv9;
      const float jv = S3.y - S1.y * S1.y * inv9;
      a += cr * cr / (iv * jv + 1e-5f); }
    { const float cr = S4.z - S1.z * S0.z * inv9;
      const float iv = S2.z - S0.z * S0.z * inv9;
      const float jv = S3.z - S1.z * S1.z * inv9;
      a += cr * cr / (iv * jv + 1e-5f); }
    { const float cr = S4.w - S1.w * S0.w * inv9;
      const float iv = S2.w - S0.w * S0.w * inv9;
      const float jv = S3.w - S1.w * S1.w * inv9;
      a += cr * cr / (iv * jv + 1e-5f); }
    return a;
}

// ---------------------------------------------------------------------------
// K2: z-running sums (registers) + x-window via double-buffered LDS with ONE
// barrier per z-step + cc + reduction. ROWS2=4 (160 thr) -> grid 1536 = 6
// blocks/CU for latency hiding; sbuf 26.9 KB.
// ---------------------------------------------------------------------------
__global__ __launch_bounds__(160) void k2_zxcc(const _Float16* __restrict__ A,
                                               double* __restrict__ acc) {
    __shared__ float sbuf[2][ROWS2][5][RW_]; // 26.88 KB
    __shared__ float red[256];
    const int tid = threadIdx.x;             // 0..159
    const int r   = tid / 40;                // 0..3
    const int xg  = tid - r * 40;            // 0..39
    const int x4  = xg * 4;                  // window start (padded idx)
    const int blk = blockIdx.x;
    const int zc  = blk % NZC2;
    const int rp  = blk / NZC2;              // 0..95
    const int gy  = rp * ROWS2 + r;          // 0..383
    const int b   = gy / H_;
    const int yy  = gy - b * H_;
    const int z0  = zc * ZCH2;

    {   // zero entire sbuf once (pads stay 0; interior overwritten per step)
        float* p = &sbuf[0][0][0][0];
        for (int i = tid; i < 2 * ROWS2 * 5 * RW_; i += 160) p[i] = 0.f;
    }

    // own data cols sit at padded offset 4 + x4
    const _Float16* Abase = A + (size_t)(b * D_) * A_Z + (size_t)yy * A_Y + 4 + x4;

    float4 s[5];
#pragma unroll
    for (int c = 0; c < 5; ++c) s[c] = make_float4(0.f, 0.f, 0.f, 0.f);
#pragma unroll
    for (int j = 0; j < 9; ++j) {            // prime slices [z0-5, z0+3]
        const int zi = z0 - 5 + j;           // z0+3 <= 153 < D_
        if (zi >= 0) {
            const _Float16* Az = Abase + (size_t)zi * A_Z;
            add4h(s[0], *(const half4*)(Az + 0 * RW_));
            add4h(s[1], *(const half4*)(Az + 1 * RW_));
            add4h(s[2], *(const half4*)(Az + 2 * RW_));
            add4h(s[3], *(const half4*)(Az + 3 * RW_));
            add4h(s[4], *(const half4*)(Az + 4 * RW_));
        }
    }
    __syncthreads();                         // LDS zero visible

    float local = 0.f;
#pragma unroll 2
    for (int k = 0; k < ZCH2; ++k) {
        const int zi = z0 + k + 4;           // block-uniform branches
        if (zi < D_) {
            const _Float16* Az = Abase + (size_t)zi * A_Z;
            add4h(s[0], *(const half4*)(Az + 0 * RW_));
            add4h(s[1], *(const half4*)(Az + 1 * RW_));
            add4h(s[2], *(const half4*)(Az + 2 * RW_));
            add4h(s[3], *(const half4*)(Az + 3 * RW_));
            add4h(s[4], *(const half4*)(Az + 4 * RW_));
        }
        const int zo = z0 + k - 5;
        if (zo >= 0) {
            const _Float16* Az = Abase + (size_t)zo * A_Z;
            sub4h(s[0], *(const half4*)(Az + 0 * RW_));
            sub4h(s[1], *(const half4*)(Az + 1 * RW_));
            sub4h(s[2], *(const half4*)(Az + 2 * RW_));
            sub4h(s[3], *(const half4*)(Az + 3 * RW_));
            sub4h(s[4], *(const half4*)(Az + 4 * RW_));
        }
        const int p = k & 1;
        *(float4*)&sbuf[p][r][0][4 + x4] = s[0];
        *(float4*)&sbuf[p][r][1][4 + x4] = s[1];
        *(float4*)&sbuf[p][r][2][4 + x4] = s[2];
        *(float4*)&sbuf[p][r][3][4 + x4] = s[3];
        *(float4*)&sbuf[p][r][4][4 + x4] = s[4];
        __syncthreads();                     // single barrier (dbuf WAR-safe)

        float4 S5[5];
#pragma unroll
        for (int c = 0; c < 5; ++c) {
            const float4 a0 = *(const float4*)&sbuf[p][r][c][x4];
            const float4 a1 = *(const float4*)&sbuf[p][r][c][x4 + 4];
            const float4 a2 = *(const float4*)&sbuf[p][r][c][x4 + 8];
            const float o0 = a0.x + a0.y + a0.z + a0.w + a1.x + a1.y + a1.z + a1.w + a2.x;
            const float o1 = o0 - a0.x + a2.y;
            const float o2 = o1 - a0.y + a2.z;
            const float o3 = o2 - a0.z + a2.w;
            S5[c] = make_float4(o0, o1, o2, o3);
        }
        local += cc4(S5[0], S5[1], S5[2], S5[3], S5[4]);
    }

    red[tid] = local;
    if (tid < 96) red[160 + tid] = 0.f;
    __syncthreads();
    for (int off = 128; off > 0; off >>= 1) {
        if (tid < off) red[tid] += red[tid + off];
        __syncthreads();
    }
    if (tid == 0) atomicAdd(acc, (double)red[0]);
}

// ---------------------------------------------------------------------------
// Fallback (workspace too small): direct clipped 9x9x9 sums per voxel.
// ---------------------------------------------------------------------------
__global__ void p_direct(const float* __restrict__ I, const float* __restrict__ J,
                         double* __restrict__ acc) {
    const long long idx = (long long)blockIdx.x * blockDim.x + threadIdx.x;
    float local = 0.f;
    if (idx < NV_) {
        const int x = (int)(idx % W_);
        long long t = idx / W_;
        const int y = (int)(t % H_);
        t /= H_;
        const int z = (int)(t % D_);
        const int b = (int)(t / D_);
        const int z0 = max(z - 4, 0), z1 = min(z + 4, D_ - 1);
        const int y0 = max(y - 4, 0), y1 = min(y + 4, H_ - 1);
        const int x0 = max(x - 4, 0), x1 = min(x + 4, W_ - 1);
        float sI = 0.f, sJ = 0.f, sI2 = 0.f, sJ2 = 0.f, sIJ = 0.f;
        for (int zz = z0; zz <= z1; ++zz)
            for (int yy = y0; yy <= y1; ++yy) {
                const size_t row = ((size_t)(b * D_ + zz) * H_ + yy) * W_;
                for (int xx = x0; xx <= x1; ++xx) {
                    const float a = I[row + xx];
                    const float bb = J[row + xx];
                    sI += a; sJ += bb; sI2 += a * a; sJ2 += bb * bb; sIJ += a * bb;
                }
            }
        const float inv9 = 1.0f / 9.0f;
        const float cross = sIJ - sJ * sI * inv9;
        const float iv    = sI2 - sI * sI * inv9;
        const float jv    = sJ2 - sJ * sJ * inv9;
        local = cross * cross / (iv * jv + 1e-5f);
    }
    __shared__ float red[256];
    red[threadIdx.x] = local;
    __syncthreads();
    for (int off = 128; off > 0; off >>= 1) {
        if (threadIdx.x < off) red[threadIdx.x] += red[threadIdx.x + off];
        __syncthreads();
    }
    if (threadIdx.x == 0) atomicAdd(acc, (double)red[0]);
}

__global__ void k_final(const double* __restrict__ acc, float* __restrict__ out) {
    out[0] = (float)(-(*acc) / (double)NV_);
}

extern "C" void kernel_launch(void* const* d_in, const int* in_sizes, int n_in,
                              void* d_out, int out_size, void* d_ws, size_t ws_size,
                              hipStream_t stream) {
    const float* I = (const float*)d_in[0];  // y_true
    const float* J = (const float*)d_in[1];  // y_pred
    float* out = (float*)d_out;

    const size_t needA = (size_t)B_ * D_ * A_Z * sizeof(_Float16);  // 103.2 MB
    if (ws_size >= 1024 + needA) {
        double* acc = (double*)d_ws;
        _Float16* A = (_Float16*)((char*)d_ws + 1024);
        k_zero<<<1, 1, 0, stream>>>(acc);
        k1_ysum<<<B_ * D_ * NYH, 320, 0, stream>>>(I, J, A);
        k2_zxcc<<<NZC2 * NRP, 160, 0, stream>>>(A, acc);
        k_final<<<1, 1, 0, stream>>>(acc, out);
    } else if (ws_size >= sizeof(double)) {
        double* acc = (double*)d_ws;
        k_zero<<<1, 1, 0, stream>>>(acc);
        p_direct<<<(int)((NV_ + 255) / 256), 256, 0, stream>>>(I, J, acc);
        k_final<<<1, 1, 0, stream>>>(acc, out);
    }
}

// Round 24
// 92.572 us; speedup vs baseline: 2.2955x; 1.1503x over previous
//
#include <hip/hip_runtime.h>

// Shape: (B=2, C=1, D=160, H=192, W=160) fp32. win=9/dim, win_size=9 (faithful bug).
#define B_ 2
#define D_ 160
#define H_ 192
#define W_ 160
#define HW_ (H_ * W_)
#define DHW_ (D_ * HW_)
#define NV_ ((long long)B_ * D_ * H_ * W_)

// K1: block = (bz, y-quarter); full W staged in LDS with zero-filled halos.
#define YH1 48
#define NYH (H_ / YH1)       // 4
#define SROWS (YH1 + 8)      // 56 staged rows
#define SSTRH (W_ + 4)       // 164 halves per LDS stage row
#define YCH1 6               // rows per thread (8 yc x 40 xg = 320 thr)

// K2: 8-row / 320-thread / single-buffer / 2-barrier (best measured form).
#define ROWS2 8
#define ZCH2 10
#define NZC2 (D_ / ZCH2)     // 16
#define LROW 168             // padded fp32 sbuf row (= RW_)

// Padded interleaved A: [bz][y][c][xpad], xpad = 4 + 160 + 4 = 168 halves.
#define RW_ 168
#define A_Y ((size_t)5 * RW_)        // 840 halves per y
#define A_Z ((size_t)H_ * A_Y)      // 161280 halves per slice

typedef _Float16 half4 __attribute__((ext_vector_type(4)));

__global__ void k_zero(double* acc) { *acc = 0.0; }

__device__ __forceinline__ void add4h(float4& d, const half4 v) {
    d.x += (float)v.x; d.y += (float)v.y; d.z += (float)v.z; d.w += (float)v.w;
}
__device__ __forceinline__ void sub4h(float4& d, const half4 v) {
    d.x -= (float)v.x; d.y -= (float)v.y; d.z -= (float)v.z; d.w -= (float)v.w;
}

// Accumulate (+/-) one staged row's 5 products into s[5] (4 x-cols).
template<int SGN>
__device__ __forceinline__ void accPr(float4 s[5], const half4 ha, const half4 hb) {
    const float4 a = make_float4((float)ha.x, (float)ha.y, (float)ha.z, (float)ha.w);
    const float4 b = make_float4((float)hb.x, (float)hb.y, (float)hb.z, (float)hb.w);
    if (SGN > 0) {
        s[0].x += a.x;     s[0].y += a.y;     s[0].z += a.z;     s[0].w += a.w;
        s[1].x += b.x;     s[1].y += b.y;     s[1].z += b.z;     s[1].w += b.w;
        s[2].x += a.x*a.x; s[2].y += a.y*a.y; s[2].z += a.z*a.z; s[2].w += a.w*a.w;
        s[3].x += b.x*b.x; s[3].y += b.y*b.y; s[3].z += b.z*b.z; s[3].w += b.w*b.w;
        s[4].x += a.x*b.x; s[4].y += a.y*b.y; s[4].z += a.z*b.z; s[4].w += a.w*b.w;
    } else {
        s[0].x -= a.x;     s[0].y -= a.y;     s[0].z -= a.z;     s[0].w -= a.w;
        s[1].x -= b.x;     s[1].y -= b.y;     s[1].z -= b.z;     s[1].w -= b.w;
        s[2].x -= a.x*a.x; s[2].y -= a.y*a.y; s[2].z -= a.z*a.z; s[2].w -= a.w*a.w;
        s[3].x -= b.x*b.x; s[3].y -= b.y*b.y; s[3].z -= b.z*b.z; s[3].w -= b.w*b.w;
        s[4].x -= a.x*b.x; s[4].y -= a.y*b.y; s[4].z -= a.z*b.z; s[4].w -= a.w*b.w;
    }
}

// ---------------------------------------------------------------------------
// K1: block = one (b,z) slice x one 48-row y-quarter. Stage 56 rows x full W
// of I,J in LDS fp16 (zero-filled halos), run y-window running sums, write
// padded interleaved fp16 A (full-line contiguous stores; edge lanes zero
// the pads). LDS 36.7 KB -> 4 blocks/CU; grid 1280. Verified in R22.
// ---------------------------------------------------------------------------
__global__ __launch_bounds__(320) void k1_ysum(const float* __restrict__ I,
                                               const float* __restrict__ J,
                                               _Float16* __restrict__ A) {
    __shared__ _Float16 sI[SROWS][SSTRH];    // 18.4 KB
    __shared__ _Float16 sJ[SROWS][SSTRH];    // 18.4 KB
    const int tid = threadIdx.x;             // 0..319
    const int yh  = blockIdx.x % NYH;
    const int bz  = blockIdx.x / NYH;        // b*D + z
    const int ylo = yh * YH1 - 4;            // staged row lr <-> global y = ylo+lr

    const float* Ib = I + (size_t)bz * HW_;
    const float* Jb = J + (size_t)bz * HW_;

#pragma unroll
    for (int i = 0; i < 7; ++i) {
        const int idx = i * 320 + tid;       // 0..2239
        const int lr  = idx / 40;
        const int g   = idx - lr * 40;
        const int gy  = ylo + lr;
        half4 hi, hj;
        hi.x = hi.y = hi.z = hi.w = (_Float16)0.f;
        hj.x = hj.y = hj.z = hj.w = (_Float16)0.f;
        if (gy >= 0 && gy < H_) {
            const float4 vi = *(const float4*)(Ib + (size_t)gy * W_ + g * 4);
            const float4 vj = *(const float4*)(Jb + (size_t)gy * W_ + g * 4);
            hi.x = (_Float16)vi.x; hi.y = (_Float16)vi.y; hi.z = (_Float16)vi.z; hi.w = (_Float16)vi.w;
            hj.x = (_Float16)vj.x; hj.y = (_Float16)vj.y; hj.z = (_Float16)vj.z; hj.w = (_Float16)vj.w;
        }
        *(half4*)&sI[lr][g * 4] = hi;
        *(half4*)&sJ[lr][g * 4] = hj;
    }
    __syncthreads();

    const int xg = tid % 40;
    const int yc = tid / 40;
    const int x4 = xg * 4;
    const int y0 = yh * YH1 + yc * YCH1;     // first output row
    const int l0 = yc * YCH1 + 4;            // its staged index

    _Float16* Ap = A + (size_t)bz * A_Z;

    float4 s[5];
#pragma unroll
    for (int c = 0; c < 5; ++c) s[c] = make_float4(0.f, 0.f, 0.f, 0.f);

#pragma unroll
    for (int j = 0; j < 8; ++j)              // prime staged rows [l0-4, l0+3]
        accPr<+1>(s, *(const half4*)&sI[l0 - 4 + j][x4], *(const half4*)&sJ[l0 - 4 + j][x4]);

    half4 zer;
    zer.x = zer.y = zer.z = zer.w = (_Float16)0.f;

#pragma unroll
    for (int k = 0; k < YCH1; ++k) {
        const int ll = l0 + k + 4;           // lead (<= 55; zero rows clip)
        accPr<+1>(s, *(const half4*)&sI[ll][x4], *(const half4*)&sJ[ll][x4]);
        if (k >= 1) {                        // trail: only rows actually added
            const int lt = l0 + k - 5;
            accPr<-1>(s, *(const half4*)&sI[lt][x4], *(const half4*)&sJ[lt][x4]);
        }
        _Float16* Ay = Ap + (size_t)(y0 + k) * A_Y;
#pragma unroll
        for (int c = 0; c < 5; ++c) {
            half4 h;
            h.x = (_Float16)s[c].x; h.y = (_Float16)s[c].y;
            h.z = (_Float16)s[c].z; h.w = (_Float16)s[c].w;
            *(half4*)(Ay + c * RW_ + 4 + x4) = h;
            if (xg == 0)  *(half4*)(Ay + c * RW_)       = zer;
            if (xg == 39) *(half4*)(Ay + c * RW_ + 164) = zer;
        }
    }
}

__device__ __forceinline__ float cc4(const float4 S0, const float4 S1, const float4 S2,
                                     const float4 S3, const float4 S4) {
    const float inv9 = 1.0f / 9.0f;
    float a = 0.f;
    { const float cr = S4.x - S1.x * S0.x * inv9;
      const float iv = S2.x - S0.x * S0.x * inv9;
      const float jv = S3.x - S1.x * S1.x * inv9;
      a += cr * cr / (iv * jv + 1e-5f); }
    { const float cr = S4.y - S1.y * S0.y * inv9;
      const float iv = S2.y - S0.y * S0.y * inv9;
      const float jv = S3.y - S1.y * S1.y * inv9;
      a += cr * cr / (iv * jv + 1e-5f); }
    { const float cr = S4.z - S1.z * S0.z * inv9;
      const float iv = S2.z - S0.z * S0.z * inv9;
      const float jv = S3.z - S1.z * S1.z * inv9;
      a += cr * cr / (iv * jv + 1e-5f); }
    { const float cr = S4.w - S1.w * S0.w * inv9;
      const float iv = S2.w - S0.w * S0.w * inv9;
      const float jv = S3.w - S1.w * S1.w * inv9;
      a += cr * cr / (iv * jv + 1e-5f); }
    return a;
}

// ---------------------------------------------------------------------------
// K2: z-running sums (registers) + x-window via single-buffered LDS (write /
// barrier / read / barrier) + cc + reduction. 8 rows x 40 lanes = 320 thr,
// z-chunk 10, sbuf 26.9 KB -> 5 blocks/CU. Best-measured k2 form (R13/R16),
// re-addressed for the padded interleaved A.
// ---------------------------------------------------------------------------
__global__ __launch_bounds__(320) void k2_zxcc(const _Float16* __restrict__ A,
                                               double* __restrict__ acc) {
    __shared__ float sbuf[ROWS2][5][LROW];   // 26.88 KB
    __shared__ float red[512];
    const int tid = threadIdx.x;             // 0..319
    const int r   = tid / 40;                // 0..7
    const int xg  = tid - r * 40;            // 0..39
    const int x4  = xg * 4;                  // window start (padded idx)
    const int blk = blockIdx.x;
    const int zc  = blk % NZC2;
    const int rp  = blk / NZC2;              // 0..47
    const int gy  = rp * ROWS2 + r;          // 0..383  (192%8==0: no b straddle)
    const int b   = gy / H_;
    const int yy  = gy - b * H_;
    const int z0  = zc * ZCH2;

    {   // zero sbuf once (pads stay 0; interior overwritten every step)
        float* p = &sbuf[0][0][0];
        for (int i = tid; i < ROWS2 * 5 * LROW; i += 320) p[i] = 0.f;
    }

    // own data cols sit at padded offset 4 + x4
    const _Float16* Abase = A + (size_t)(b * D_) * A_Z + (size_t)yy * A_Y + 4 + x4;

    float4 s[5];
#pragma unroll
    for (int c = 0; c < 5; ++c) s[c] = make_float4(0.f, 0.f, 0.f, 0.f);
#pragma unroll
    for (int j = 0; j < 9; ++j) {            // prime slices [z0-5, z0+3]
        const int zi = z0 - 5 + j;           // z0+3 <= 153 < D_
        if (zi >= 0) {
            const _Float16* Az = Abase + (size_t)zi * A_Z;
            add4h(s[0], *(const half4*)(Az + 0 * RW_));
            add4h(s[1], *(const half4*)(Az + 1 * RW_));
            add4h(s[2], *(const half4*)(Az + 2 * RW_));
            add4h(s[3], *(const half4*)(Az + 3 * RW_));
            add4h(s[4], *(const half4*)(Az + 4 * RW_));
        }
    }
    __syncthreads();                         // LDS zero visible

    float local = 0.f;
    for (int k = 0; k < ZCH2; ++k) {
        const int zi = z0 + k + 4;           // block-uniform branches
        if (zi < D_) {
            const _Float16* Az = Abase + (size_t)zi * A_Z;
            add4h(s[0], *(const half4*)(Az + 0 * RW_));
            add4h(s[1], *(const half4*)(Az + 1 * RW_));
            add4h(s[2], *(const half4*)(Az + 2 * RW_));
            add4h(s[3], *(const half4*)(Az + 3 * RW_));
            add4h(s[4], *(const half4*)(Az + 4 * RW_));
        }
        const int zo = z0 + k - 5;
        if (zo >= 0) {
            const _Float16* Az = Abase + (size_t)zo * A_Z;
            sub4h(s[0], *(const half4*)(Az + 0 * RW_));
            sub4h(s[1], *(const half4*)(Az + 1 * RW_));
            sub4h(s[2], *(const half4*)(Az + 2 * RW_));
            sub4h(s[3], *(const half4*)(Az + 3 * RW_));
            sub4h(s[4], *(const half4*)(Az + 4 * RW_));
        }
        *(float4*)&sbuf[r][0][4 + x4] = s[0];
        *(float4*)&sbuf[r][1][4 + x4] = s[1];
        *(float4*)&sbuf[r][2][4 + x4] = s[2];
        *(float4*)&sbuf[r][3][4 + x4] = s[3];
        *(float4*)&sbuf[r][4][4 + x4] = s[4];
        __syncthreads();

        float4 S5[5];
#pragma unroll
        for (int c = 0; c < 5; ++c) {
            const float4 a0 = *(const float4*)&sbuf[r][c][x4];
            const float4 a1 = *(const float4*)&sbuf[r][c][x4 + 4];
            const float4 a2 = *(const float4*)&sbuf[r][c][x4 + 8];
            const float o0 = a0.x + a0.y + a0.z + a0.w + a1.x + a1.y + a1.z + a1.w + a2.x;
            const float o1 = o0 - a0.x + a2.y;
            const float o2 = o1 - a0.y + a2.z;
            const float o3 = o2 - a0.z + a2.w;
            S5[c] = make_float4(o0, o1, o2, o3);
        }
        local += cc4(S5[0], S5[1], S5[2], S5[3], S5[4]);
        __syncthreads();                     // WAR: next step overwrites sbuf
    }

    red[tid] = local;
    if (tid < 192) red[320 + tid] = 0.f;
    __syncthreads();
    for (int off = 256; off > 0; off >>= 1) {
        if (tid < off) red[tid] += red[tid + off];
        __syncthreads();
    }
    if (tid == 0) atomicAdd(acc, (double)red[0]);
}

// ---------------------------------------------------------------------------
// Fallback (workspace too small): direct clipped 9x9x9 sums per voxel.
// ---------------------------------------------------------------------------
__global__ void p_direct(const float* __restrict__ I, const float* __restrict__ J,
                         double* __restrict__ acc) {
    const long long idx = (long long)blockIdx.x * blockDim.x + threadIdx.x;
    float local = 0.f;
    if (idx < NV_) {
        const int x = (int)(idx % W_);
        long long t = idx / W_;
        const int y = (int)(t % H_);
        t /= H_;
        const int z = (int)(t % D_);
        const int b = (int)(t / D_);
        const int z0 = max(z - 4, 0), z1 = min(z + 4, D_ - 1);
        const int y0 = max(y - 4, 0), y1 = min(y + 4, H_ - 1);
        const int x0 = max(x - 4, 0), x1 = min(x + 4, W_ - 1);
        float sI = 0.f, sJ = 0.f, sI2 = 0.f, sJ2 = 0.f, sIJ = 0.f;
        for (int zz = z0; zz <= z1; ++zz)
            for (int yy = y0; yy <= y1; ++yy) {
                const size_t row = ((size_t)(b * D_ + zz) * H_ + yy) * W_;
                for (int xx = x0; xx <= x1; ++xx) {
                    const float a = I[row + xx];
                    const float bb = J[row + xx];
                    sI += a; sJ += bb; sI2 += a * a; sJ2 += bb * bb; sIJ += a * bb;
                }
            }
        const float inv9 = 1.0f / 9.0f;
        const float cross = sIJ - sJ * sI * inv9;
        const float iv    = sI2 - sI * sI * inv9;
        const float jv    = sJ2 - sJ * sJ * inv9;
        local = cross * cross / (iv * jv + 1e-5f);
    }
    __shared__ float red[256];
    red[threadIdx.x] = local;
    __syncthreads();
    for (int off = 128; off > 0; off >>= 1) {
        if (threadIdx.x < off) red[threadIdx.x] += red[threadIdx.x + off];
        __syncthreads();
    }
    if (threadIdx.x == 0) atomicAdd(acc, (double)red[0]);
}

__global__ void k_final(const double* __restrict__ acc, float* __restrict__ out) {
    out[0] = (float)(-(*acc) / (double)NV_);
}

extern "C" void kernel_launch(void* const* d_in, const int* in_sizes, int n_in,
                              void* d_out, int out_size, void* d_ws, size_t ws_size,
                              hipStream_t stream) {
    const float* I = (const float*)d_in[0];  // y_true
    const float* J = (const float*)d_in[1];  // y_pred
    float* out = (float*)d_out;

    const size_t needA = (size_t)B_ * D_ * A_Z * sizeof(_Float16);  // 103.2 MB
    if (ws_size >= 1024 + needA) {
        double* acc = (double*)d_ws;
        _Float16* A = (_Float16*)((char*)d_ws + 1024);
        k_zero<<<1, 1, 0, stream>>>(acc);
        k1_ysum<<<B_ * D_ * NYH, 320, 0, stream>>>(I, J, A);
        k2_zxcc<<<NZC2 * (B_ * H_ / ROWS2), 320, 0, stream>>>(A, acc);
        k_final<<<1, 1, 0, stream>>>(acc, out);
    } else if (ws_size >= sizeof(double)) {
        double* acc = (double*)d_ws;
        k_zero<<<1, 1, 0, stream>>>(acc);
        p_direct<<<(int)((NV_ + 255) / 256), 256, 0, stream>>>(I, J, acc);
        k_final<<<1, 1, 0, stream>>>(acc, out);
    }
}